// Round 7
// baseline (211.872 us; speedup 1.0000x reference)
//
#include <hip/hip_runtime.h>
#include <math.h>

// PPO loss with GAE.  B=4096 rows, T=2048 steps, fp32 inputs.
// Inputs: 0 rewards(B,T) 1 values(B,T+1) 2 ref_probs(UNUSED) 3 old_probs(B,T)
//         4 curr_probs(B,T) 5 masks(B,T)
// Output: 4 floats: total, ppo, 0.5*value_loss, 0.01*entropy_loss
//
// R7: test = register-throttled MLP. One row per WAVE (4096 waves), no
// __syncthreads/LDS in gae at all. Row processed as 8 slabs of 256 elems,
// right-to-left, with slab k-1's global loads issued before slab k's
// shuffle-scan (vmcnt vs lgkmcnt overlap). Affine carry composed across
// slabs via lane-0 broadcast. Dispatches 4 -> 3: stats reduction fused into
// ppo (identical deterministic fp64 tree per block); finalize_out recomputes
// sum2 itself.

#define GAMMA     0.99f
#define LAM       0.95f
#define CLIP_LO   0.8f
#define CLIP_HI   1.2f
#define EPSF      1e-9f

constexpr int BB = 4096;
constexpr int TT = 2048;
constexpr long long NN = (long long)BB * TT;   // 8388608
constexpr int GAE_BLOCKS = BB / 4;             // 1024 blocks x 4 waves = 1 row/wave
constexpr int PPO_BLOCKS = 2048;

// ws layout:
//  [64, 64+32K)    gae partials: 4096 x float2 (sum_adv, sum_adv2) per ROW
//  [.., +16K)      ppo partials: 2048 x float2 (sum_min, sum_ent)
//  [49216, +16.8M) adv in bf16
static constexpr size_t GAE_PART_OFF = 64;
static constexpr size_t PPO_PART_OFF = GAE_PART_OFF + BB * sizeof(float2);
static constexpr size_t ADV_OFF      = PPO_PART_OFF + PPO_BLOCKS * sizeof(float2);

__device__ __forceinline__ unsigned bf16_rne(float x) {
    unsigned u = __float_as_uint(x);
    u += 0x7FFFu + ((u >> 16) & 1u);
    return u >> 16;
}

// ---------------------------------------------------------------- K1: GAE scan
// One row per wave. 8 slabs of 256 elems (4/lane), scanned k=7..0 with a
// 1-slab-deep load pipeline. No LDS, no barriers.
__global__ __launch_bounds__(256, 4) void gae_kernel(
    const float* __restrict__ rewards,
    const float* __restrict__ values,
    const float* __restrict__ masks,
    uint2* __restrict__ advb,          // 4 bf16 per uint2, flat layout
    float2* __restrict__ partials)     // one per row
{
    const int tid  = threadIdx.x;
    const int lane = tid & 63;
    const int wave = tid >> 6;
    const int row  = blockIdx.x * 4 + wave;

    const float* rrow = rewards + (size_t)row * TT;
    const float* mrow = masks   + (size_t)row * TT;
    const float* vrow = values  + (size_t)row * (TT + 1);

    // prefetch slab 7
    int e = 256 * 7 + 4 * lane;
    float4 rc = *(const float4*)(rrow + e);
    float4 mc = *(const float4*)(mrow + e);
    float vc0 = vrow[e], vc1 = vrow[e + 1], vc2 = vrow[e + 2], vc3 = vrow[e + 3];
    float head = vrow[2048];           // same addr all lanes -> broadcast fetch

    float V  = 0.0f;                   // adv entering from the right (adv[2048]=0)
    float s1 = 0.f, s2 = 0.f;

    for (int k = 7; k >= 0; --k) {
        // ---- issue next slab's loads before doing any compute ----
        float4 rn, mn;
        float vn0 = 0.f, vn1 = 0.f, vn2 = 0.f, vn3 = 0.f;
        if (k > 0) {
            const int en = 256 * (k - 1) + 4 * lane;
            rn  = *(const float4*)(rrow + en);
            mn  = *(const float4*)(mrow + en);
            vn0 = vrow[en]; vn1 = vrow[en + 1]; vn2 = vrow[en + 2]; vn3 = vrow[en + 3];
        }

        // boundary v for current slab: v[e+4] = next lane's vc0; lane 63 <- head
        float v4 = __shfl_down(vc0, 1, 64);
        if (lane == 63) v4 = head;
        float nexthead = __shfl(vc0, 0, 64);   // v[256k] for slab k-1's lane 63

        // ---- local affine over 4 elems: f(x) = la[0] + S[0]*x ----
        float vv[5] = {vc0, vc1, vc2, vc3, v4};
        float rr[4] = {rc.x, rc.y, rc.z, rc.w};
        float mm[4] = {mc.x, mc.y, mc.z, mc.w};
        float la[4], S[4];
        {
            float d[4], c[4];
#pragma unroll
            for (int j = 0; j < 4; ++j) {
                d[j] = rr[j] + GAMMA * vv[j + 1] * mm[j] - vv[j];
                c[j] = (GAMMA * LAM) * mm[j];
            }
            la[3] = d[3]; S[3] = c[3];
#pragma unroll
            for (int j = 2; j >= 0; --j) {
                la[j] = d[j] + c[j] * la[j + 1];
                S[j]  = c[j] * S[j + 1];
            }
        }

        // ---- wave suffix scan of chunk affines (verified R4-R6) ----
        float A = S[0], Bv = la[0];
#pragma unroll
        for (int d = 1; d < 64; d <<= 1) {
            float A2 = __shfl_down(A,  d, 64);
            float B2 = __shfl_down(Bv, d, 64);
            if (lane + d < 64) { Bv = Bv + A * B2; A = A * A2; }
        }
        float A1 = __shfl_down(A,  1, 64);
        float B1 = __shfl_down(Bv, 1, 64);
        float carry = (lane < 63) ? (B1 + A1 * V) : V;

        float a0 = la[0] + S[0] * carry;
        float a1 = la[1] + S[1] * carry;
        float a2 = la[2] + S[2] * carry;
        float a3 = la[3] + S[3] * carry;
        s1 += a0 + a1 + a2 + a3;
        s2 += a0 * a0 + a1 * a1 + a2 * a2 + a3 * a3;

        uint2 pk = {bf16_rne(a0) | (bf16_rne(a1) << 16),
                    bf16_rne(a2) | (bf16_rne(a3) << 16)};
        advb[(size_t)row * 512 + 64 * k + lane] = pk;

        // slab-exit value for slab k-1: adv[256k] = F_0(V), from lane 0
        float vtmp = Bv + A * V;
        V    = __shfl(vtmp, 0, 64);
        head = nexthead;

        rc = rn; mc = mn;
        vc0 = vn0; vc1 = vn1; vc2 = vn2; vc3 = vn3;
    }

    // ---- wave reduce s1,s2 -> one float2 per row ----
#pragma unroll
    for (int off = 32; off > 0; off >>= 1) {
        s1 += __shfl_down(s1, off, 64);
        s2 += __shfl_down(s2, off, 64);
    }
    if (lane == 0) partials[row] = make_float2(s1, s2);
}

// ------------------------------------------------- K2: ppo surrogate + entropy
// Prologue: every block redundantly reduces the 4096 gae partials (32 KB,
// L2-hot) with the SAME deterministic fp64 tree -> identical mean/inv.
__global__ __launch_bounds__(256, 4) void ppo_kernel(
    const float* __restrict__ adv_bf16,   // raw bf16 pairs, read as uint2
    const float* __restrict__ oldp,
    const float* __restrict__ currp,
    const float2* __restrict__ gaep,
    float2* __restrict__ partials)
{
    const int tid = threadIdx.x;
    const int b   = blockIdx.x;

    __shared__ double l1[256], l2[256];
    {
        double d1 = 0.0, d2 = 0.0;
        for (int i = tid; i < BB; i += 256) {
            float2 p = gaep[i];
            d1 += (double)p.x;
            d2 += (double)p.y;
        }
        l1[tid] = d1; l2[tid] = d2;
        __syncthreads();
        for (int st = 128; st > 0; st >>= 1) {
            if (tid < st) { l1[tid] += l1[tid + st]; l2[tid] += l2[tid + st]; }
            __syncthreads();
        }
    }
    const double S1 = l1[0], S2 = l2[0];
    const double var = (S2 - S1 * S1 / (double)NN) / (double)(NN - 1);  // ddof=1
    const float mean = (float)(S1 / (double)NN);
    const float inv  = (float)(1.0 / (sqrt(var) + 1e-9));

    const uint2*  a2 = (const uint2*)adv_bf16;   // 4 bf16 per uint2
    const float4* o4 = (const float4*)oldp;
    const float4* c4 = (const float4*)currp;

    uint2  Aq[4]; float4 Of[4], Cf[4];
#pragma unroll
    for (int k = 0; k < 4; ++k) {
        int i = b * 1024 + k * 256 + tid;
        Aq[k] = a2[i]; Of[k] = o4[i]; Cf[k] = c4[i];
    }

    float sm = 0.f, se = 0.f;
#pragma unroll
    for (int k = 0; k < 4; ++k) {
        float av[4] = {__uint_as_float(Aq[k].x << 16),
                       __uint_as_float(Aq[k].x & 0xFFFF0000u),
                       __uint_as_float(Aq[k].y << 16),
                       __uint_as_float(Aq[k].y & 0xFFFF0000u)};
        float ov[4] = {Of[k].x, Of[k].y, Of[k].z, Of[k].w};
        float cv[4] = {Cf[k].x, Cf[k].y, Cf[k].z, Cf[k].w};
#pragma unroll
        for (int j = 0; j < 4; ++j) {
            float an    = (av[j] - mean) * inv;
            float ratio = cv[j] * __builtin_amdgcn_rcpf(ov[j] + EPSF);
            float rc    = fminf(fmaxf(ratio, CLIP_LO), CLIP_HI);
            sm += fminf(ratio * an, rc * an);
            se += cv[j] * __logf(cv[j] + EPSF);
        }
    }

#pragma unroll
    for (int off = 32; off > 0; off >>= 1) {
        sm += __shfl_down(sm, off, 64);
        se += __shfl_down(se, off, 64);
    }
    __shared__ float w1[4], w2[4];
    const int wave = tid >> 6, lane = tid & 63;
    if (lane == 0) { w1[wave] = sm; w2[wave] = se; }
    __syncthreads();
    if (tid == 0) {
        float2 p = {w1[0] + w1[1] + w1[2] + w1[3],
                    w2[0] + w2[1] + w2[2] + w2[3]};
        partials[b] = p;
    }
}

// ------------------------- K3: reduce ppo partials (+sum2) -> 4 output scalars
__global__ __launch_bounds__(256) void finalize_out(
    const float2* __restrict__ pp,
    const float2* __restrict__ gaep,
    float* __restrict__ out)
{
    const int tid = threadIdx.x;
    __shared__ double l1[256], l2[256], l3[256];
    double s1 = 0.0, s2 = 0.0, s3 = 0.0;
    for (int i = tid; i < PPO_BLOCKS; i += 256) {
        float2 p = pp[i];
        s1 += (double)p.x;
        s2 += (double)p.y;
    }
    for (int i = tid; i < BB; i += 256) s3 += (double)gaep[i].y;
    l1[tid] = s1; l2[tid] = s2; l3[tid] = s3;
    __syncthreads();
    for (int st = 128; st > 0; st >>= 1) {
        if (tid < st) {
            l1[tid] += l1[tid + st];
            l2[tid] += l2[tid + st];
            l3[tid] += l3[tid + st];
        }
        __syncthreads();
    }
    if (tid == 0) {
        double invN = 1.0 / (double)NN;
        double vl   = 0.5  * (l3[0] * invN);   // 0.5 * mean(raw_adv^2)
        double ppo  = -(l1[0] * invN);
        double ent  = -0.01 * (l2[0] * invN);
        out[0] = (float)(ppo + vl + ent);
        out[1] = (float)ppo;
        out[2] = (float)vl;
        out[3] = (float)ent;
    }
}

extern "C" void kernel_launch(void* const* d_in, const int* in_sizes, int n_in,
                              void* d_out, int out_size, void* d_ws, size_t ws_size,
                              hipStream_t stream) {
    const float* rewards = (const float*)d_in[0];
    const float* values  = (const float*)d_in[1];
    // d_in[2] = ref_probs: unused by the reference
    const float* oldp    = (const float*)d_in[3];
    const float* currp   = (const float*)d_in[4];
    const float* masks   = (const float*)d_in[5];

    float2* gaep = (float2*)((char*)d_ws + GAE_PART_OFF);
    float2* ppop = (float2*)((char*)d_ws + PPO_PART_OFF);
    uint2*  advb = (uint2*)((char*)d_ws + ADV_OFF);
    float*  out  = (float*)d_out;

    gae_kernel<<<GAE_BLOCKS, 256, 0, stream>>>(rewards, values, masks, advb, gaep);
    ppo_kernel<<<PPO_BLOCKS, 256, 0, stream>>>((const float*)advb, oldp, currp, gaep, ppop);
    finalize_out<<<1, 256, 0, stream>>>(ppop, gaep, out);
}